// Round 1
// baseline (729.207 us; speedup 1.0000x reference)
//
#include <hip/hip_runtime.h>
#include <cstdint>
#include <cstddef>

// Problem: B=1, S=4096, HIDDEN=2048, HEADS=16, KVH=4, HD=128, CHUNK=1024.
// Pipeline: X->bf16; W transposed->bf16 [N][K]; GEMM Q (N=2048), GEMM KV (N=1024,
// K cols 0..511, V cols 512..1023); YaRN RoPE in-place on Q,K; chunked
// ring-attention reproducing the reference's (non-standard) cross-chunk merge;
// final GEMM attn@Wo -> fp32 out.
//
// ws layout (bytes):            size
//   Xbf    @ 0                  16,777,216
//   Qbf    @ 16,777,216         16,777,216
//   KVbf   @ 33,554,432          8,388,608
//   attn   @ 41,943,040         16,777,216
//   Wqt    @ 58,720,256          8,388,608
//   Wkvt   @ 67,108,864          4,194,304
//   Wot    @ 71,303,168          8,388,608
//   total ~79.7 MB

typedef unsigned short u16;
typedef unsigned int u32;
typedef float f32x4 __attribute__((ext_vector_type(4)));
typedef __bf16 bf16x8 __attribute__((ext_vector_type(8)));

__device__ __forceinline__ u16 f2bf(float f) {
    union { float f; u32 u; } v; v.f = f;
    u32 u = v.u;
    u += 0x7fffu + ((u >> 16) & 1u);   // round-to-nearest-even
    return (u16)(u >> 16);
}

__device__ __forceinline__ float bf2f(u16 b) {
    union { u32 u; float f; } v; v.u = ((u32)b) << 16;
    return v.f;
}

// async global->LDS, 16B per lane; LDS dest = wave-uniform base + lane*16
__device__ __forceinline__ void load16_to_lds(const void* g, void* l) {
    __builtin_amdgcn_global_load_lds((const __attribute__((address_space(1))) u32*)g,
                                     (__attribute__((address_space(3))) u32*)l,
                                     16, 0, 0);
}

#define MFMA16(a, b, c) __builtin_amdgcn_mfma_f32_16x16x32_bf16((a), (b), (c), 0, 0, 0)

// ---------------------------------------------------------------- convert X
__global__ __launch_bounds__(256) void convert_f32_bf16(const float* __restrict__ X,
                                                        u16* __restrict__ Y) {
    const int i = (blockIdx.x * 256 + threadIdx.x) * 4;
    const float4 v = *(const float4*)(X + i);
    union { u16 s[4]; uint2 u; } pk;
    pk.s[0] = f2bf(v.x); pk.s[1] = f2bf(v.y); pk.s[2] = f2bf(v.z); pk.s[3] = f2bf(v.w);
    *(uint2*)(Y + i) = pk.u;
}

// -------------------------------------------- transpose W [K=2048][N] -> Wt [N][2048] bf16
__global__ __launch_bounds__(256) void transpose_w(const float* __restrict__ W,
                                                   u16* __restrict__ Wt, int N) {
    __shared__ float tile[64][65];
    const int n0 = blockIdx.x * 64, k0 = blockIdx.y * 64;
    const int tc = threadIdx.x & 63, tr = threadIdx.x >> 6;
#pragma unroll
    for (int i = 0; i < 64; i += 4)
        tile[tc][tr + i] = W[(size_t)(k0 + tr + i) * N + n0 + tc];
    __syncthreads();
#pragma unroll
    for (int i = 0; i < 64; i += 4)
        Wt[(size_t)(n0 + tr + i) * 2048 + k0 + tc] = f2bf(tile[tr + i][tc]);
}

// ---------------------------------------------------------------- GEMM C = A * Bt^T
// A [M][K] bf16 (k-contig), Bt [N][K] bf16 (k-contig). 128x128 block tile, 4 waves 2x2,
// wave = 64x64 = 4x4 tiles of 16x16x32 MFMA. BK=32, global_load_lds staging.
__device__ __forceinline__ void store_out(float* p, float v) { *p = v; }
__device__ __forceinline__ void store_out(u16* p, float v) { *p = f2bf(v); }

template <typename OutT>
__global__ __launch_bounds__(256) void gemm_bt(const u16* __restrict__ A,
                                               const u16* __restrict__ Bt,
                                               OutT* __restrict__ C,
                                               int M, int N, int K) {
    __shared__ __align__(16) u16 sA[128 * 32];
    __shared__ __align__(16) u16 sB[128 * 32];
    const int t = threadIdx.x;
    const int lane = t & 63, w = t >> 6;
    const int quad = lane >> 4, l15 = lane & 15;
    const int m0 = blockIdx.x << 7, n0 = blockIdx.y << 7;
    const int wr = (w >> 1) << 6, wc = (w & 1) << 6;
    f32x4 acc[4][4] = {};
    for (int k0 = 0; k0 < K; k0 += 32) {
        __syncthreads();
#pragma unroll
        for (int r = 0; r < 2; ++r) {
            const int chunk = (r * 4 + w) * 64 + lane;  // 0..511
            const int row = chunk >> 2;
            const int e0 = (chunk & 3) << 3;
            load16_to_lds(A + (size_t)(m0 + row) * K + k0 + e0, sA + (size_t)(r * 4 + w) * 512);
            load16_to_lds(Bt + (size_t)(n0 + row) * K + k0 + e0, sB + (size_t)(r * 4 + w) * 512);
        }
        __syncthreads();
        bf16x8 af[4], bb[4];
#pragma unroll
        for (int i = 0; i < 4; ++i)
            af[i] = *(const bf16x8*)(sA + (wr + i * 16 + l15) * 32 + quad * 8);
#pragma unroll
        for (int j = 0; j < 4; ++j)
            bb[j] = *(const bf16x8*)(sB + (wc + j * 16 + l15) * 32 + quad * 8);
#pragma unroll
        for (int i = 0; i < 4; ++i)
#pragma unroll
            for (int j = 0; j < 4; ++j)
                acc[i][j] = MFMA16(af[i], bb[j], acc[i][j]);
    }
#pragma unroll
    for (int i = 0; i < 4; ++i)
#pragma unroll
        for (int j = 0; j < 4; ++j) {
            const int row = m0 + wr + i * 16 + quad * 4;
            const int col = n0 + wc + j * 16 + l15;
#pragma unroll
            for (int r = 0; r < 4; ++r)
                store_out(C + (size_t)(row + r) * N + col, acc[i][j][r]);
        }
}

// ---------------------------------------------------------------- YaRN RoPE (in place)
// Q [4096][2048] (16 heads), K = KV cols 0..511 (4 kv heads). low=18, high=35,
// mscale = 0.1*ln(16)+1. inv = (1-s)*interp + s*extrap, s = clamp((i-18)/17).
__global__ __launch_bounds__(256) void rope_kernel(u16* __restrict__ Q,
                                                   u16* __restrict__ KV,
                                                   const int* __restrict__ pos_ids) {
    const int idx = blockIdx.x * 256 + threadIdx.x;
    const int NQ = 4096 * 16 * 64;
    u16* p;
    int s, i;
    if (idx < NQ) {
        s = idx >> 10;
        const int hi = idx & 1023;
        const int h = hi >> 6;
        i = hi & 63;
        p = Q + (size_t)s * 2048 + h * 128 + i;
    } else {
        const int k = idx - NQ;
        if (k >= 4096 * 4 * 64) return;
        s = k >> 8;
        const int hi = k & 255;
        const int h = hi >> 6;
        i = hi & 63;
        p = KV + (size_t)s * 1024 + h * 128 + i;
    }
    const float pf = (float)pos_ids[s];
    const float fi = (float)i;
    const float pos_freq = powf(500000.0f, fi * (1.0f / 64.0f));
    const float inv_ex = 1.0f / pos_freq;
    const float inv_in = inv_ex * (1.0f / 16.0f);
    const float sm = fminf(fmaxf((fi - 18.0f) * (1.0f / 17.0f), 0.0f), 1.0f);
    const float inv = (1.0f - sm) * inv_in + sm * inv_ex;
    const float ph = pf * inv;
    const float MS = 1.2772588722239781f;
    const float cs = cosf(ph) * MS, sn = sinf(ph) * MS;
    const float x1 = bf2f(p[0]), x2 = bf2f(p[64]);
    p[0] = f2bf(x1 * cs - x2 * sn);
    p[64] = f2bf(x2 * cs + x1 * sn);
}

// ---------------------------------------------------------------- attention
// Grid (64, 16): block = 64 q rows of one head; 4 waves x 16 rows.
// Reproduces reference ring-attention: proper online softmax within each 1024-chunk,
// then the reference's merge: d = lg*e_g + lc*e_c + 1e-10; o = o*(lg/d) + oc*e_c/d.
__global__ __launch_bounds__(256) void attn_kernel(const u16* __restrict__ Q,
                                                   const u16* __restrict__ KV,
                                                   u16* __restrict__ Oa) {
    __shared__ __align__(16) u16 sQ[4 * 64 * 32];   // [kc][row][32]
    __shared__ __align__(16) u16 sK[4 * 64 * 32];
    __shared__ __align__(16) u16 sVt[128 * 72];     // [d][key] padded
    __shared__ __align__(16) u16 sP[4 * 16 * 72];   // per-wave [qrow][key] padded

    const int t = threadIdx.x;
    const int lane = t & 63, w = t >> 6;
    const int quad = lane >> 4, l15 = lane & 15;
    const int q0 = blockIdx.x << 6;
    const int h = blockIdx.y, kvh = h >> 2;

#pragma unroll
    for (int r = 0; r < 4; ++r) {   // stage Q tile once
        const int chunk = (r * 4 + w) * 64 + lane;   // 0..1023
        const int kc = chunk >> 8;
        const int row = (chunk & 255) >> 2;
        const int e0 = (chunk & 3) << 3;
        load16_to_lds(Q + (size_t)(q0 + row) * 2048 + h * 128 + kc * 32 + e0,
                      sQ + (size_t)(r * 4 + w) * 512);
    }

    float m_g[4], l_g[4];
    f32x4 o_g[8] = {};
#pragma unroll
    for (int r = 0; r < 4; ++r) { m_g[r] = -1e30f; l_g[r] = 0.0f; }

    const float SCALE = 0.08838834764831845f;  // 128^-0.5
    const int qrow_base = q0 + w * 16 + quad * 4;

    for (int c = 0; c < 4; ++c) {
        const int kv0 = c << 10;
        if (kv0 > q0) break;   // fully-masked chunk: effect <= 1e-10 relative, skip
        float m_c[4], l_c[4];
        f32x4 o_c[8] = {};
#pragma unroll
        for (int r = 0; r < 4; ++r) { m_c[r] = -1e30f; l_c[r] = 0.0f; }
        const int nj = ((q0 - kv0) >> 6) + 1;
        const int jmax = nj < 16 ? nj : 16;

        for (int j = 0; j < jmax; ++j) {
            const int kt0 = kv0 + (j << 6);
            __syncthreads();   // prev tile consumed; also drains Q stage on 1st iter
#pragma unroll
            for (int r = 0; r < 4; ++r) {   // stage K tile
                const int chunk = (r * 4 + w) * 64 + lane;
                const int kc = chunk >> 8;
                const int row = (chunk & 255) >> 2;
                const int e0 = (chunk & 3) << 3;
                load16_to_lds(KV + (size_t)(kt0 + row) * 1024 + kvh * 128 + kc * 32 + e0,
                              sK + (size_t)(r * 4 + w) * 512);
            }
#pragma unroll
            for (int r = 0; r < 4; ++r) {   // stage V transposed
                const int d0 = r * 32 + w * 8;
                const uint4 vv = *(const uint4*)(KV + (size_t)(kt0 + lane) * 1024 + 512 + kvh * 128 + d0);
                const u16* pv = (const u16*)&vv;
#pragma unroll
                for (int i = 0; i < 8; ++i) sVt[(d0 + i) * 72 + lane] = pv[i];
            }
            __syncthreads();

            // S = Q K^T for this wave's 16 rows x 64 keys
            f32x4 sacc[4] = {};
#pragma unroll
            for (int ks = 0; ks < 4; ++ks) {
                const bf16x8 af = *(const bf16x8*)(sQ + ks * 2048 + (w * 16 + l15) * 32 + quad * 8);
#pragma unroll
                for (int j4 = 0; j4 < 4; ++j4) {
                    const bf16x8 bk = *(const bf16x8*)(sK + ks * 2048 + (j4 * 16 + l15) * 32 + quad * 8);
                    sacc[j4] = MFMA16(af, bk, sacc[j4]);
                }
            }

            float sv[4][4];
            const bool diag = (kt0 == q0);
#pragma unroll
            for (int j4 = 0; j4 < 4; ++j4) {
                const int kcol = kt0 + j4 * 16 + l15;
#pragma unroll
                for (int r = 0; r < 4; ++r) {
                    float x = sacc[j4][r] * SCALE;
                    if (diag && kcol > qrow_base + r) x = -1e30f;
                    sv[j4][r] = x;
                }
            }

            // within-chunk online softmax (correct rescaling)
#pragma unroll
            for (int r = 0; r < 4; ++r) {
                float mx = fmaxf(fmaxf(sv[0][r], sv[1][r]), fmaxf(sv[2][r], sv[3][r]));
#pragma unroll
                for (int off = 1; off < 16; off <<= 1) mx = fmaxf(mx, __shfl_xor(mx, off, 64));
                const float mn = fmaxf(m_c[r], mx);
                const float alpha = __expf(m_c[r] - mn);
                float ps = 0.0f;
#pragma unroll
                for (int j4 = 0; j4 < 4; ++j4) {
                    const float p = __expf(sv[j4][r] - mn);
                    sv[j4][r] = p;
                    ps += p;
                }
#pragma unroll
                for (int off = 1; off < 16; off <<= 1) ps += __shfl_xor(ps, off, 64);
                l_c[r] = l_c[r] * alpha + ps;
                m_c[r] = mn;
#pragma unroll
                for (int dt = 0; dt < 8; ++dt) o_c[dt][r] *= alpha;
            }

            // P -> LDS (C-layout to A-layout round trip)
#pragma unroll
            for (int j4 = 0; j4 < 4; ++j4)
#pragma unroll
                for (int r = 0; r < 4; ++r)
                    sP[w * 1152 + (quad * 4 + r) * 72 + j4 * 16 + l15] = f2bf(sv[j4][r]);

            // O_c += P @ V
#pragma unroll
            for (int ks = 0; ks < 2; ++ks) {
                const bf16x8 ap = *(const bf16x8*)(sP + w * 1152 + l15 * 72 + ks * 32 + quad * 8);
#pragma unroll
                for (int dt = 0; dt < 8; ++dt) {
                    const bf16x8 bv = *(const bf16x8*)(sVt + (dt * 16 + l15) * 72 + ks * 32 + quad * 8);
                    o_c[dt] = MFMA16(ap, bv, o_c[dt]);
                }
            }
        } // key tiles

        // reference's cross-chunk merge (note: old-output factor is l_g/d, NOT a/d)
#pragma unroll
        for (int r = 0; r < 4; ++r) {
            const float mn = fmaxf(m_g[r], m_c[r]);
            const float a = l_g[r] * __expf(m_g[r] - mn);
            const float eC = __expf(m_c[r] - mn);
            const float sE = l_c[r] * eC;
            const float d = a + sE + 1e-10f;
            const float f_old = l_g[r] / d;
            const float f_new = eC / d;
#pragma unroll
            for (int dt = 0; dt < 8; ++dt)
                o_g[dt][r] = o_g[dt][r] * f_old + o_c[dt][r] * f_new;
            l_g[r] = a + sE;
            m_g[r] = mn;
        }
    } // chunks

#pragma unroll
    for (int dt = 0; dt < 8; ++dt)
#pragma unroll
        for (int r = 0; r < 4; ++r)
            Oa[(size_t)(q0 + w * 16 + quad * 4 + r) * 2048 + h * 128 + dt * 16 + l15] =
                f2bf(o_g[dt][r]);
}

// ---------------------------------------------------------------- launch
extern "C" void kernel_launch(void* const* d_in, const int* in_sizes, int n_in,
                              void* d_out, int out_size, void* d_ws, size_t ws_size,
                              hipStream_t stream) {
    const float* X  = (const float*)d_in[0];
    const int* pos  = (const int*)d_in[1];
    const float* Wq = (const float*)d_in[2];
    const float* Wk = (const float*)d_in[3];
    const float* Wv = (const float*)d_in[4];
    const float* Wo = (const float*)d_in[5];
    float* out = (float*)d_out;
    char* ws = (char*)d_ws;

    u16* Xbf  = (u16*)(ws);
    u16* Qbf  = (u16*)(ws + 16777216);
    u16* KVbf = (u16*)(ws + 33554432);
    u16* attn = (u16*)(ws + 41943040);
    u16* Wqt  = (u16*)(ws + 58720256);
    u16* Wkvt = (u16*)(ws + 67108864);
    u16* Wot  = (u16*)(ws + 71303168);

    convert_f32_bf16<<<8192, 256, 0, stream>>>(X, Xbf);
    transpose_w<<<dim3(32, 32), 256, 0, stream>>>(Wq, Wqt, 2048);
    transpose_w<<<dim3(8, 32), 256, 0, stream>>>(Wk, Wkvt, 512);
    transpose_w<<<dim3(8, 32), 256, 0, stream>>>(Wv, Wkvt + (size_t)512 * 2048, 512);
    transpose_w<<<dim3(32, 32), 256, 0, stream>>>(Wo, Wot, 2048);

    gemm_bt<u16><<<dim3(32, 16), 256, 0, stream>>>(Xbf, Wqt, Qbf, 4096, 2048, 2048);
    gemm_bt<u16><<<dim3(32, 8), 256, 0, stream>>>(Xbf, Wkvt, KVbf, 4096, 1024, 2048);

    rope_kernel<<<20480, 256, 0, stream>>>(Qbf, KVbf, pos);

    attn_kernel<<<dim3(64, 16), 256, 0, stream>>>(Qbf, KVbf, attn);

    gemm_bt<float><<<dim3(32, 16), 256, 0, stream>>>(attn, Wot, out, 4096, 2048, 2048);
}

// Round 2
// 555.453 us; speedup vs baseline: 1.3128x; 1.3128x over previous
//
#include <hip/hip_runtime.h>
#include <cstdint>
#include <cstddef>

// B=1, S=4096, HIDDEN=2048, HEADS=16, KVH=4, HD=128, CHUNK=1024.
// Pipeline: X->bf16; W^T bf16; GEMM Q / GEMM KV; YaRN RoPE; V pre-transpose;
// chunk-parallel attention partials (proper online softmax within chunk);
// sequential merge reproducing the reference's non-standard cross-chunk rule;
// final GEMM attn@Wo -> fp32.
//
// ws arena (bytes), with liveness-based overlays:
//   part  @ 0          41,943,040   (fp16 partials; overlays Xbf/Wqt/Wkvt, dead by then)
//     Xbf   @ 0            16,777,216  [dead after GEMMs]
//     Wqt   @ 16,777,216    8,388,608  [dead after Q GEMM]
//     Wkvt  @ 25,165,824    4,194,304  [dead after KV GEMM]
//   Qbf   @ 41,943,040 16,777,216   (attn bf16 overlays after partial phase)
//   KVbf  @ 58,720,256  8,388,608
//   Vt    @ 67,108,864  4,194,304   ([kvh][128][4096] bf16)
//   ml    @ 71,303,168  1,310,720   (fp32 m,l per partial row)
//   Wot   @ 72,613,888  8,388,608
//   total 81,002,496  (~77.3 MB)

typedef unsigned short u16;
typedef unsigned int u32;
typedef float f32x4 __attribute__((ext_vector_type(4)));
typedef __bf16 bf16x8 __attribute__((ext_vector_type(8)));

__device__ __forceinline__ u16 f2bf(float f) {
    union { float f; u32 u; } v; v.f = f;
    u32 u = v.u;
    u += 0x7fffu + ((u >> 16) & 1u);
    return (u16)(u >> 16);
}
__device__ __forceinline__ float bf2f(u16 b) {
    union { u32 u; float f; } v; v.u = ((u32)b) << 16;
    return v.f;
}
__device__ __forceinline__ u16 f2h(float f) {
    union { _Float16 h; u16 u; } v; v.h = (_Float16)f; return v.u;
}
__device__ __forceinline__ float h2f(u16 u) {
    union { u16 u; _Float16 h; } v; v.u = u; return (float)v.h;
}

__device__ __forceinline__ void load16_to_lds(const void* g, void* l) {
    __builtin_amdgcn_global_load_lds((const __attribute__((address_space(1))) u32*)g,
                                     (__attribute__((address_space(3))) u32*)l,
                                     16, 0, 0);
}

#define MFMA16(a, b, c) __builtin_amdgcn_mfma_f32_16x16x32_bf16((a), (b), (c), 0, 0, 0)

// ---------------------------------------------------------------- convert X
__global__ __launch_bounds__(256) void convert_f32_bf16(const float* __restrict__ X,
                                                        u16* __restrict__ Y) {
    const int i = (blockIdx.x * 256 + threadIdx.x) * 4;
    const float4 v = *(const float4*)(X + i);
    union { u16 s[4]; uint2 u; } pk;
    pk.s[0] = f2bf(v.x); pk.s[1] = f2bf(v.y); pk.s[2] = f2bf(v.z); pk.s[3] = f2bf(v.w);
    *(uint2*)(Y + i) = pk.u;
}

// -------------------------------------------- transpose W [K=2048][N] -> Wt [N][2048] bf16
__global__ __launch_bounds__(256) void transpose_w(const float* __restrict__ W,
                                                   u16* __restrict__ Wt, int N) {
    __shared__ float tile[64][65];
    const int n0 = blockIdx.x * 64, k0 = blockIdx.y * 64;
    const int tc = threadIdx.x & 63, tr = threadIdx.x >> 6;
#pragma unroll
    for (int i = 0; i < 64; i += 4)
        tile[tc][tr + i] = W[(size_t)(k0 + tr + i) * N + n0 + tc];
    __syncthreads();
#pragma unroll
    for (int i = 0; i < 64; i += 4)
        Wt[(size_t)(n0 + tr + i) * 2048 + k0 + tc] = f2bf(tile[tr + i][tc]);
}

// ---------------------------------------------------------------- GEMM C = A * Bt^T
__device__ __forceinline__ void store_out(float* p, float v) { *p = v; }
__device__ __forceinline__ void store_out(u16* p, float v) { *p = f2bf(v); }

template <typename OutT>
__global__ __launch_bounds__(256) void gemm_bt(const u16* __restrict__ A,
                                               const u16* __restrict__ Bt,
                                               OutT* __restrict__ C,
                                               int M, int N, int K) {
    __shared__ __align__(16) u16 sA[128 * 32];
    __shared__ __align__(16) u16 sB[128 * 32];
    const int t = threadIdx.x;
    const int lane = t & 63, w = t >> 6;
    const int quad = lane >> 4, l15 = lane & 15;
    const int m0 = blockIdx.x << 7, n0 = blockIdx.y << 7;
    const int wr = (w >> 1) << 6, wc = (w & 1) << 6;
    f32x4 acc[4][4] = {};
    for (int k0 = 0; k0 < K; k0 += 32) {
        __syncthreads();
#pragma unroll
        for (int r = 0; r < 2; ++r) {
            const int chunk = (r * 4 + w) * 64 + lane;
            const int row = chunk >> 2;
            const int e0 = (chunk & 3) << 3;
            load16_to_lds(A + (size_t)(m0 + row) * K + k0 + e0, sA + (size_t)(r * 4 + w) * 512);
            load16_to_lds(Bt + (size_t)(n0 + row) * K + k0 + e0, sB + (size_t)(r * 4 + w) * 512);
        }
        __syncthreads();
        bf16x8 af[4], bb[4];
#pragma unroll
        for (int i = 0; i < 4; ++i)
            af[i] = *(const bf16x8*)(sA + (wr + i * 16 + l15) * 32 + quad * 8);
#pragma unroll
        for (int j = 0; j < 4; ++j)
            bb[j] = *(const bf16x8*)(sB + (wc + j * 16 + l15) * 32 + quad * 8);
#pragma unroll
        for (int i = 0; i < 4; ++i)
#pragma unroll
            for (int j = 0; j < 4; ++j)
                acc[i][j] = MFMA16(af[i], bb[j], acc[i][j]);
    }
#pragma unroll
    for (int i = 0; i < 4; ++i)
#pragma unroll
        for (int j = 0; j < 4; ++j) {
            const int row = m0 + wr + i * 16 + quad * 4;
            const int col = n0 + wc + j * 16 + l15;
#pragma unroll
            for (int r = 0; r < 4; ++r)
                store_out(C + (size_t)(row + r) * N + col, acc[i][j][r]);
        }
}

// ---------------------------------------------------------------- YaRN RoPE (in place)
__global__ __launch_bounds__(256) void rope_kernel(u16* __restrict__ Q,
                                                   u16* __restrict__ KV,
                                                   const int* __restrict__ pos_ids) {
    const int idx = blockIdx.x * 256 + threadIdx.x;
    const int NQ = 4096 * 16 * 64;
    u16* p;
    int s, i;
    if (idx < NQ) {
        s = idx >> 10;
        const int hi = idx & 1023;
        const int h = hi >> 6;
        i = hi & 63;
        p = Q + (size_t)s * 2048 + h * 128 + i;
    } else {
        const int k = idx - NQ;
        if (k >= 4096 * 4 * 64) return;
        s = k >> 8;
        const int hi = k & 255;
        const int h = hi >> 6;
        i = hi & 63;
        p = KV + (size_t)s * 1024 + h * 128 + i;
    }
    const float pf = (float)pos_ids[s];
    const float fi = (float)i;
    const float pos_freq = powf(500000.0f, fi * (1.0f / 64.0f));
    const float inv_ex = 1.0f / pos_freq;
    const float inv_in = inv_ex * (1.0f / 16.0f);
    const float sm = fminf(fmaxf((fi - 18.0f) * (1.0f / 17.0f), 0.0f), 1.0f);
    const float inv = (1.0f - sm) * inv_in + sm * inv_ex;
    const float ph = pf * inv;
    const float MS = 1.2772588722239781f;
    const float cs = cosf(ph) * MS, sn = sinf(ph) * MS;
    const float x1 = bf2f(p[0]), x2 = bf2f(p[64]);
    p[0] = f2bf(x1 * cs - x2 * sn);
    p[64] = f2bf(x2 * cs + x1 * sn);
}

// ---------------------------------------------------------------- V pre-transpose
// KV [4096][1024] (V = cols 512+kvh*128+d) -> Vt [kvh][128][4096] bf16
__global__ __launch_bounds__(256) void transpose_v(const u16* __restrict__ KV,
                                                   u16* __restrict__ Vt) {
    __shared__ u16 tile[64 * 72];
    const int t = threadIdx.x;
    const int k0 = blockIdx.x * 64, d0 = blockIdx.y * 64, kvh = blockIdx.z;
#pragma unroll
    for (int k = 0; k < 4; ++k) {
        const int u = t + k * 256;
        const int key = u >> 4, dg = u & 15;
        const uint2 v = *(const uint2*)(KV + (size_t)(k0 + key) * 1024 + 512 + kvh * 128 + d0 + dg * 4);
        *(uint2*)(tile + key * 72 + dg * 4) = v;
    }
    __syncthreads();
#pragma unroll
    for (int k = 0; k < 4; ++k) {
        const int u = t + k * 256;
        const int d = u >> 4, kg = u & 15;
        union { u16 s[4]; uint2 v; } pk;
#pragma unroll
        for (int i = 0; i < 4; ++i) pk.s[i] = tile[(kg * 4 + i) * 72 + d];
        *(uint2*)(Vt + (size_t)(kvh * 128 + d0 + d) * 4096 + k0 + kg * 4) = pk.v;
    }
}

// ---------------------------------------------------------------- attention partials
// grid (160, 16): x = (qb,c) pair within head, y = head. Each block: 64 q rows x one
// 1024-chunk, proper online softmax within the chunk, emits normalized fp16 o-hat
// plus fp32 (m,l) per row. Pair layout: group g=qb>>4 has chunks c=0..g;
// base pairs for group g: {0,16,48,96}; within: (qb&15)*(g+1)+c.
__global__ __launch_bounds__(256) void attn_partial(const u16* __restrict__ Q,
                                                    const u16* __restrict__ KV,
                                                    const u16* __restrict__ Vt,
                                                    u16* __restrict__ part,
                                                    float* __restrict__ ml) {
    __shared__ __align__(16) u16 sK[4 * 64 * 32];   // 16 KB (also Q staging)
    __shared__ __align__(16) u16 sVt[128 * 72];     // 18 KB [d][key] padded
    __shared__ __align__(16) u16 sP[4 * 16 * 72];   // 9.2 KB per-wave P

    const int t = threadIdx.x;
    const int lane = t & 63, w = t >> 6;
    const int quad = lane >> 4, l15 = lane & 15;
    const int p = blockIdx.x, h = blockIdx.y, kvh = h >> 2;

    int qb, c;
    if (p < 16)      { qb = p;                 c = 0; }
    else if (p < 48) { const int r = p - 16;   qb = 16 + (r >> 1); c = r & 1; }
    else if (p < 96) { const int r = p - 48;   qb = 32 + r / 3;    c = r - (r / 3) * 3; }
    else             { const int r = p - 96;   qb = 48 + (r >> 2); c = r & 3; }
    const int q0 = qb << 6, kv0 = c << 10;
    const int g = qb >> 4;
    const int jmax = (c == g) ? ((qb & 15) + 1) : 16;

    // stage Q tile into sK, move to registers
#pragma unroll
    for (int r = 0; r < 4; ++r) {
        const int chunk = (r * 4 + w) * 64 + lane;
        const int kc = chunk >> 8;
        const int row = (chunk & 255) >> 2;
        const int e0 = (chunk & 3) << 3;
        load16_to_lds(Q + (size_t)(q0 + row) * 2048 + h * 128 + kc * 32 + e0,
                      sK + (size_t)(r * 4 + w) * 512);
    }
    __syncthreads();
    bf16x8 af[4];
#pragma unroll
    for (int ks = 0; ks < 4; ++ks)
        af[ks] = *(const bf16x8*)(sK + ks * 2048 + (w * 16 + l15) * 32 + quad * 8);

    float m_c[4], l_c[4];
    f32x4 o_c[8] = {};
#pragma unroll
    for (int r = 0; r < 4; ++r) { m_c[r] = -1e30f; l_c[r] = 0.0f; }

    const float SCALE = 0.08838834764831845f;  // 128^-0.5
    const int qrow_base = q0 + w * 16 + quad * 4;

    for (int j = 0; j < jmax; ++j) {
        const int kt0 = kv0 + (j << 6);
        __syncthreads();   // prev tile consumed (and Q reg reads drained on j==0)
#pragma unroll
        for (int r = 0; r < 4; ++r) {   // stage K tile (async, direct to LDS)
            const int chunk = (r * 4 + w) * 64 + lane;
            const int kc = chunk >> 8;
            const int row = (chunk & 255) >> 2;
            const int e0 = (chunk & 3) << 3;
            load16_to_lds(KV + (size_t)(kt0 + row) * 1024 + kvh * 128 + kc * 32 + e0,
                          sK + (size_t)(r * 4 + w) * 512);
        }
        // stage V^T tile: 4x (uint4 load + ds_write_b128)
        uint4 vv[4];
#pragma unroll
        for (int k = 0; k < 4; ++k) {
            const int u = t + k * 256;
            const int d = u >> 3, p8 = u & 7;
            vv[k] = *(const uint4*)(Vt + (size_t)(kvh * 128 + d) * 4096 + kt0 + p8 * 8);
        }
#pragma unroll
        for (int k = 0; k < 4; ++k) {
            const int u = t + k * 256;
            const int d = u >> 3, p8 = u & 7;
            *(uint4*)(sVt + d * 72 + p8 * 8) = vv[k];
        }
        __syncthreads();

        // S = Q K^T (wave's 16 rows x 64 keys)
        f32x4 sacc[4] = {};
#pragma unroll
        for (int ks = 0; ks < 4; ++ks) {
#pragma unroll
            for (int j4 = 0; j4 < 4; ++j4) {
                const bf16x8 bk = *(const bf16x8*)(sK + ks * 2048 + (j4 * 16 + l15) * 32 + quad * 8);
                sacc[j4] = MFMA16(af[ks], bk, sacc[j4]);
            }
        }

        float sv[4][4];
        const bool diag = (kt0 == q0);
#pragma unroll
        for (int j4 = 0; j4 < 4; ++j4) {
            const int kcol = kt0 + j4 * 16 + l15;
#pragma unroll
            for (int r = 0; r < 4; ++r) {
                float x = sacc[j4][r] * SCALE;
                if (diag && kcol > qrow_base + r) x = -1e30f;
                sv[j4][r] = x;
            }
        }

        // online softmax within chunk (correct rescaling)
#pragma unroll
        for (int r = 0; r < 4; ++r) {
            float mx = fmaxf(fmaxf(sv[0][r], sv[1][r]), fmaxf(sv[2][r], sv[3][r]));
#pragma unroll
            for (int off = 1; off < 16; off <<= 1) mx = fmaxf(mx, __shfl_xor(mx, off, 64));
            const float mn = fmaxf(m_c[r], mx);
            const float alpha = __expf(m_c[r] - mn);
            float ps = 0.0f;
#pragma unroll
            for (int j4 = 0; j4 < 4; ++j4) {
                const float pe = __expf(sv[j4][r] - mn);
                sv[j4][r] = pe;
                ps += pe;
            }
#pragma unroll
            for (int off = 1; off < 16; off <<= 1) ps += __shfl_xor(ps, off, 64);
            l_c[r] = l_c[r] * alpha + ps;
            m_c[r] = mn;
#pragma unroll
            for (int dt = 0; dt < 8; ++dt) o_c[dt][r] *= alpha;
        }

        // P: C-layout -> A-layout via per-wave LDS
#pragma unroll
        for (int j4 = 0; j4 < 4; ++j4)
#pragma unroll
            for (int r = 0; r < 4; ++r)
                sP[w * 1152 + (quad * 4 + r) * 72 + j4 * 16 + l15] = f2bf(sv[j4][r]);

        // O_c += P @ V
#pragma unroll
        for (int ks = 0; ks < 2; ++ks) {
            const bf16x8 ap = *(const bf16x8*)(sP + w * 1152 + l15 * 72 + ks * 32 + quad * 8);
#pragma unroll
            for (int dt = 0; dt < 8; ++dt) {
                const bf16x8 bv = *(const bf16x8*)(sVt + (dt * 16 + l15) * 72 + ks * 32 + quad * 8);
                o_c[dt] = MFMA16(ap, bv, o_c[dt]);
            }
        }
    }

    // epilogue: normalized o-hat (fp16) + per-row (m,l) fp32
    const int tile = h * 160 + p;
#pragma unroll
    for (int r = 0; r < 4; ++r) {
        const float invl = 1.0f / l_c[r];
        const int lr = w * 16 + quad * 4 + r;
#pragma unroll
        for (int dt = 0; dt < 8; ++dt)
            part[(size_t)tile * 8192 + lr * 128 + dt * 16 + l15] = f2h(o_c[dt][r] * invl);
        if (l15 == 0) {
            ml[(size_t)tile * 128 + lr * 2] = m_c[r];
            ml[(size_t)tile * 128 + lr * 2 + 1] = l_c[r];
        }
    }
}

// ---------------------------------------------------------------- merge partials
// grid (64, 16); thread: row = t&63, cols (t>>6)*32..+31. Applies reference's
// merge IN CHUNK ORDER: d = a + sE + 1e-10; o = o*(l_g/d) + ohat*(l_c*eC/d).
__global__ __launch_bounds__(256) void attn_merge(const u16* __restrict__ part,
                                                  const float* __restrict__ ml,
                                                  u16* __restrict__ attn) {
    const int t = threadIdx.x;
    const int qb = blockIdx.x, h = blockIdx.y;
    const int g = qb >> 4;
    const int row = t & 63, col0 = (t >> 6) * 32;
    const int base_pair[4] = {0, 16, 48, 96};
    const int pair0 = base_pair[g] + (qb & 15) * (g + 1);

    float o[32];
#pragma unroll
    for (int i = 0; i < 32; ++i) o[i] = 0.0f;
    float m_g = -1e30f, l_g = 0.0f;

    for (int c = 0; c <= g; ++c) {
        const int tile = h * 160 + pair0 + c;
        const float m_c = ml[(size_t)tile * 128 + row * 2];
        const float l_c = ml[(size_t)tile * 128 + row * 2 + 1];
        union { uint4 v; u16 s[8]; } u4[4];
#pragma unroll
        for (int k = 0; k < 4; ++k)
            u4[k].v = *(const uint4*)(part + (size_t)tile * 8192 + row * 128 + col0 + k * 8);
        const float mn = fmaxf(m_g, m_c);
        const float a = l_g * __expf(m_g - mn);
        const float eC = __expf(m_c - mn);
        const float sE = l_c * eC;
        const float d = a + sE + 1e-10f;
        const float f_old = l_g / d;
        const float f_new = l_c * eC / d;
#pragma unroll
        for (int i = 0; i < 32; ++i)
            o[i] = o[i] * f_old + h2f(u4[i >> 3].s[i & 7]) * f_new;
        l_g = a + sE;
        m_g = mn;
    }

    union { u16 s[8]; uint4 v; } pk;
    u16* dst = attn + (size_t)(qb * 64 + row) * 2048 + h * 128 + col0;
#pragma unroll
    for (int k = 0; k < 4; ++k) {
#pragma unroll
        for (int i = 0; i < 8; ++i) pk.s[i] = f2bf(o[k * 8 + i]);
        *(uint4*)(dst + k * 8) = pk.v;
    }
}

// ---------------------------------------------------------------- launch
extern "C" void kernel_launch(void* const* d_in, const int* in_sizes, int n_in,
                              void* d_out, int out_size, void* d_ws, size_t ws_size,
                              hipStream_t stream) {
    const float* X  = (const float*)d_in[0];
    const int* pos  = (const int*)d_in[1];
    const float* Wq = (const float*)d_in[2];
    const float* Wk = (const float*)d_in[3];
    const float* Wv = (const float*)d_in[4];
    const float* Wo = (const float*)d_in[5];
    float* out = (float*)d_out;
    char* ws = (char*)d_ws;

    u16*   part = (u16*)(ws);                      // 41,943,040 B
    u16*   Xbf  = (u16*)(ws);                      // overlay (dead before part)
    u16*   Wqt  = (u16*)(ws + 16777216);
    u16*   Wkvt = (u16*)(ws + 25165824);
    u16*   Qbf  = (u16*)(ws + 41943040);
    u16*   attn = (u16*)(ws + 41943040);           // overlay Qbf (dead after partials)
    u16*   KVbf = (u16*)(ws + 58720256);
    u16*   Vt   = (u16*)(ws + 67108864);
    float* ml   = (float*)(ws + 71303168);
    u16*   Wot  = (u16*)(ws + 72613888);

    convert_f32_bf16<<<8192, 256, 0, stream>>>(X, Xbf);
    transpose_w<<<dim3(32, 32), 256, 0, stream>>>(Wq, Wqt, 2048);
    transpose_w<<<dim3(8, 32), 256, 0, stream>>>(Wk, Wkvt, 512);
    transpose_w<<<dim3(8, 32), 256, 0, stream>>>(Wv, Wkvt + (size_t)512 * 2048, 512);
    transpose_w<<<dim3(32, 32), 256, 0, stream>>>(Wo, Wot, 2048);

    gemm_bt<u16><<<dim3(32, 16), 256, 0, stream>>>(Xbf, Wqt, Qbf, 4096, 2048, 2048);
    gemm_bt<u16><<<dim3(32, 8), 256, 0, stream>>>(Xbf, Wkvt, KVbf, 4096, 1024, 2048);

    rope_kernel<<<20480, 256, 0, stream>>>(Qbf, KVbf, pos);
    transpose_v<<<dim3(64, 2, 4), 256, 0, stream>>>(KVbf, Vt);

    attn_partial<<<dim3(160, 16), 256, 0, stream>>>(Qbf, KVbf, Vt, part, ml);
    attn_merge<<<dim3(64, 16), 256, 0, stream>>>(part, ml, attn);

    gemm_bt<float><<<dim3(32, 16), 256, 0, stream>>>(attn, Wot, out, 4096, 2048, 2048);
}

// Round 3
// 501.733 us; speedup vs baseline: 1.4534x; 1.1071x over previous
//
#include <hip/hip_runtime.h>
#include <cstdint>
#include <cstddef>

// B=1, S=4096, HIDDEN=2048, HEADS=16, KVH=4, HD=128, CHUNK=1024.
// R3: frag-ordered LDS (conflict-free b128 reads, glds-compatible) for attention
// and GEMMs; S^T/O^T transposed-MFMA attention (per-lane softmax state, 4 shuffles
// per tile); longest-first chunk-parallel partials; reference-exact cross-chunk merge.
//
// ws arena (bytes), liveness overlays:
//   part  @ 0          41,943,040   (overlays Xbf/Wqt/Wkvt)
//   Qbf   @ 41,943,040 16,777,216   (attn overlays after partials)
//   KVbf  @ 58,720,256  8,388,608
//   Vt    @ 67,108,864  4,194,304   ([kvh][128][4096] bf16)
//   ml    @ 71,303,168  1,310,720
//   Wot   @ 72,613,888  8,388,608
//   total 81,002,496 (~77.3 MB)

typedef unsigned short u16;
typedef unsigned int u32;
typedef float f32x4 __attribute__((ext_vector_type(4)));
typedef __bf16 bf16x8 __attribute__((ext_vector_type(8)));

__device__ __forceinline__ u16 f2bf(float f) {
    union { float f; u32 u; } v; v.f = f;
    u32 u = v.u;
    u += 0x7fffu + ((u >> 16) & 1u);
    return (u16)(u >> 16);
}
__device__ __forceinline__ float bf2f(u16 b) {
    union { u32 u; float f; } v; v.u = ((u32)b) << 16;
    return v.f;
}
__device__ __forceinline__ u16 f2h(float f) {
    union { _Float16 h; u16 u; } v; v.h = (_Float16)f; return v.u;
}
__device__ __forceinline__ float h2f(u16 u) {
    union { u16 u; _Float16 h; } v; v.u = u; return (float)v.h;
}

__device__ __forceinline__ void load16_to_lds(const void* g, void* l) {
    __builtin_amdgcn_global_load_lds((const __attribute__((address_space(1))) u32*)g,
                                     (__attribute__((address_space(3))) u32*)l,
                                     16, 0, 0);
}

#define MFMA16(a, b, c) __builtin_amdgcn_mfma_f32_16x16x32_bf16((a), (b), (c), 0, 0, 0)

// ---------------------------------------------------------------- convert X
__global__ __launch_bounds__(256) void convert_f32_bf16(const float* __restrict__ X,
                                                        u16* __restrict__ Y) {
    const int i = (blockIdx.x * 256 + threadIdx.x) * 4;
    const float4 v = *(const float4*)(X + i);
    union { u16 s[4]; uint2 u; } pk;
    pk.s[0] = f2bf(v.x); pk.s[1] = f2bf(v.y); pk.s[2] = f2bf(v.z); pk.s[3] = f2bf(v.w);
    *(uint2*)(Y + i) = pk.u;
}

// -------------------------------------------- transpose W [K=2048][N] -> Wt [N][2048] bf16
__global__ __launch_bounds__(256) void transpose_w(const float* __restrict__ W,
                                                   u16* __restrict__ Wt, int N) {
    __shared__ float tile[64][65];
    const int n0 = blockIdx.x * 64, k0 = blockIdx.y * 64;
    const int tc = threadIdx.x & 63, tr = threadIdx.x >> 6;
#pragma unroll
    for (int i = 0; i < 64; i += 4)
        tile[tc][tr + i] = W[(size_t)(k0 + tr + i) * N + n0 + tc];
    __syncthreads();
#pragma unroll
    for (int i = 0; i < 64; i += 4)
        Wt[(size_t)(n0 + tr + i) * 2048 + k0 + tc] = f2bf(tile[tr + i][tc]);
}

// ---------------------------------------------------------------- GEMM C = A * Bt^T
// Frag-ordered LDS: sA/sB hold 8 frags of 1 KB (64 lanes x 16 B) each; reads are
// ds_read_b128 at frag_base + lane*16 -> conflict-free; staging via glds width=16.
__device__ __forceinline__ void store_out(float* p, float v) { *p = v; }
__device__ __forceinline__ void store_out(u16* p, float v) { *p = f2bf(v); }

template <typename OutT>
__global__ __launch_bounds__(256) void gemm_bt(const u16* __restrict__ A,
                                               const u16* __restrict__ Bt,
                                               OutT* __restrict__ C,
                                               int M, int N, int K) {
    __shared__ __align__(16) u16 sA[8192];
    __shared__ __align__(16) u16 sB[8192];
    const int t = threadIdx.x;
    const int lane = t & 63, w = t >> 6;
    const int quad = lane >> 4, l15 = lane & 15;
    const int m0 = blockIdx.x << 7, n0 = blockIdx.y << 7;
    const int wr4 = (w >> 1) * 4, wc4 = (w & 1) * 4;   // frag-group bases
    f32x4 acc[4][4] = {};
    for (int k0 = 0; k0 < K; k0 += 32) {
        __syncthreads();
#pragma unroll
        for (int r = 0; r < 2; ++r) {
            const int f = w * 2 + r;   // frag id 0..7 = 16-row group
            load16_to_lds(A + (size_t)(m0 + f * 16 + l15) * K + k0 + quad * 8, sA + f * 512);
            load16_to_lds(Bt + (size_t)(n0 + f * 16 + l15) * K + k0 + quad * 8, sB + f * 512);
        }
        __syncthreads();
        bf16x8 af[4], bb[4];
#pragma unroll
        for (int i = 0; i < 4; ++i)
            af[i] = *(const bf16x8*)(sA + (wr4 + i) * 512 + lane * 8);
#pragma unroll
        for (int j = 0; j < 4; ++j)
            bb[j] = *(const bf16x8*)(sB + (wc4 + j) * 512 + lane * 8);
#pragma unroll
        for (int i = 0; i < 4; ++i)
#pragma unroll
            for (int j = 0; j < 4; ++j)
                acc[i][j] = MFMA16(af[i], bb[j], acc[i][j]);
    }
#pragma unroll
    for (int i = 0; i < 4; ++i)
#pragma unroll
        for (int j = 0; j < 4; ++j) {
            const int row = m0 + (w >> 1) * 64 + i * 16 + quad * 4;
            const int col = n0 + (w & 1) * 64 + j * 16 + l15;
#pragma unroll
            for (int r = 0; r < 4; ++r)
                store_out(C + (size_t)(row + r) * N + col, acc[i][j][r]);
        }
}

// ---------------------------------------------------------------- YaRN RoPE (in place)
__global__ __launch_bounds__(256) void rope_kernel(u16* __restrict__ Q,
                                                   u16* __restrict__ KV,
                                                   const int* __restrict__ pos_ids) {
    const int idx = blockIdx.x * 256 + threadIdx.x;
    const int NQ = 4096 * 16 * 64;
    u16* p;
    int s, i;
    if (idx < NQ) {
        s = idx >> 10;
        const int hi = idx & 1023;
        const int h = hi >> 6;
        i = hi & 63;
        p = Q + (size_t)s * 2048 + h * 128 + i;
    } else {
        const int k = idx - NQ;
        if (k >= 4096 * 4 * 64) return;
        s = k >> 8;
        const int hi = k & 255;
        const int h = hi >> 6;
        i = hi & 63;
        p = KV + (size_t)s * 1024 + h * 128 + i;
    }
    const float pf = (float)pos_ids[s];
    const float fi = (float)i;
    const float pos_freq = powf(500000.0f, fi * (1.0f / 64.0f));
    const float inv_ex = 1.0f / pos_freq;
    const float inv_in = inv_ex * (1.0f / 16.0f);
    const float sm = fminf(fmaxf((fi - 18.0f) * (1.0f / 17.0f), 0.0f), 1.0f);
    const float inv = (1.0f - sm) * inv_in + sm * inv_ex;
    const float ph = pf * inv;
    const float MS = 1.2772588722239781f;
    const float cs = cosf(ph) * MS, sn = sinf(ph) * MS;
    const float x1 = bf2f(p[0]), x2 = bf2f(p[64]);
    p[0] = f2bf(x1 * cs - x2 * sn);
    p[64] = f2bf(x2 * cs + x1 * sn);
}

// ---------------------------------------------------------------- V pre-transpose
// KV [4096][1024] (V = cols 512+kvh*128+d) -> Vt [kvh][128][4096] bf16
__global__ __launch_bounds__(256) void transpose_v(const u16* __restrict__ KV,
                                                   u16* __restrict__ Vt) {
    __shared__ u16 tile[64 * 72];
    const int t = threadIdx.x;
    const int k0 = blockIdx.x * 64, d0 = blockIdx.y * 64, kvh = blockIdx.z;
#pragma unroll
    for (int k = 0; k < 4; ++k) {
        const int u = t + k * 256;
        const int key = u >> 4, dg = u & 15;
        const uint2 v = *(const uint2*)(KV + (size_t)(k0 + key) * 1024 + 512 + kvh * 128 + d0 + dg * 4);
        *(uint2*)(tile + key * 72 + dg * 4) = v;
    }
    __syncthreads();
#pragma unroll
    for (int k = 0; k < 4; ++k) {
        const int u = t + k * 256;
        const int d = u >> 4, kg = u & 15;
        union { u16 s[4]; uint2 v; } pk;
#pragma unroll
        for (int i = 0; i < 4; ++i) pk.s[i] = tile[(kg * 4 + i) * 72 + d];
        *(uint2*)(Vt + (size_t)(kvh * 128 + d0 + d) * 4096 + k0 + kg * 4) = pk.v;
    }
}

// ---------------------------------------------------------------- attention partials
// grid 2560 (unit-major: bid = u*16 + h, units sorted longest-first). Each block:
// 64 q rows x one 1024-chunk (<=16 key-tiles). S^T = K*Q^T (softmax state per-lane,
// qrow = l15), O^T = V^T*P^T. Frag-ordered LDS: sK/sV 16 frags x 1 KB; sP per-wave
// 1 KB B-frag staging. Emits normalized fp16 o-hat [d][qrow] + fp32 (m,l) per row.
__global__ __launch_bounds__(256, 4) void attn_partial(const u16* __restrict__ Q,
                                                       const u16* __restrict__ KV,
                                                       const u16* __restrict__ Vt,
                                                       u16* __restrict__ part,
                                                       float* __restrict__ ml) {
    __shared__ __align__(16) u16 sK[8192];   // 16 KB: Q then K frags
    __shared__ __align__(16) u16 sV[8192];   // 16 KB: V^T frags
    __shared__ __align__(16) u16 sP[2048];   // 4 KB: per-wave P^T B-frag

    const int t = threadIdx.x;
    const int lane = t & 63, w = t >> 6;
    const int quad = lane >> 4, l15 = lane & 15;
    const int bid = blockIdx.x;
    const int u = bid >> 4, h = bid & 15, kvh = h >> 2;

    int qb, c;
    if (u < 16)      { qb = 16 + u; c = 0; }
    else if (u < 48) { const int r = u - 16; qb = 32 + (r >> 1); c = r & 1; }
    else if (u < 96) { const int r = u - 48; const int q3 = r / 3; qb = 48 + q3; c = r - q3 * 3; }
    else             { const int r = u - 96; const int g2 = r & 3; const int k = 16 - (r >> 2);
                       qb = (g2 << 4) + k - 1; c = g2; }
    const int g = qb >> 4;
    const int q0 = qb << 6, kv0 = c << 10;
    const int jmax = (c == g) ? ((qb & 15) + 1) : 16;

    // stage Q frag-order into sK (wave w owns frags w*4+kc, rows w*16+l15)
    {
        const u16* gq = Q + (size_t)(q0 + w * 16 + l15) * 2048 + h * 128 + quad * 8;
#pragma unroll
        for (int kc = 0; kc < 4; ++kc)
            load16_to_lds(gq + kc * 32, sK + (w * 4 + kc) * 512);
    }
    __syncthreads();
    bf16x8 af[4];
#pragma unroll
    for (int kc = 0; kc < 4; ++kc)
        af[kc] = *(const bf16x8*)(sK + (w * 4 + kc) * 512 + lane * 8);

    float m_c = -1e30f, l_c = 0.0f;
    f32x4 o_c[8] = {};
    const float SCALE = 0.08838834764831845f;  // 128^-0.5
    const int qrow = q0 + w * 16 + l15;

    for (int j = 0; j < jmax; ++j) {
        const int kt0 = kv0 + (j << 6);
        __syncthreads();   // prior tile fully consumed (incl. Q-frag reads on j==0)
        // K frags: wave w stages (j4=w, kc=r); V frags: wave w stages f2=w*4+r
        {
            const u16* gk = KV + (size_t)(kt0 + w * 16 + l15) * 1024 + kvh * 128 + quad * 8;
#pragma unroll
            for (int r = 0; r < 4; ++r)
                load16_to_lds(gk + r * 32, sK + (w * 4 + r) * 512);
#pragma unroll
            for (int r = 0; r < 4; ++r) {
                const int dt = w * 2 + (r >> 1), ks = r & 1;
                load16_to_lds(Vt + (size_t)(kvh * 128 + dt * 16 + l15) * 4096 + kt0 + ks * 32 + quad * 8,
                              sV + (w * 4 + r) * 512);
            }
        }
        __syncthreads();

        // S^T = K * Q^T : 16 MFMA, A-frag reads conflict-free
        f32x4 sacc[4] = {};
#pragma unroll
        for (int j4 = 0; j4 < 4; ++j4)
#pragma unroll
            for (int kc = 0; kc < 4; ++kc) {
                const bf16x8 kf = *(const bf16x8*)(sK + (j4 * 4 + kc) * 512 + lane * 8);
                sacc[j4] = MFMA16(kf, af[kc], sacc[j4]);
            }

        // scores: per-lane qrow = l15; key = kt0 + j4*16 + quad*4 + r
        float sv[4][4];
        if (kt0 == q0) {   // diagonal tile (uniform branch)
#pragma unroll
            for (int j4 = 0; j4 < 4; ++j4)
#pragma unroll
                for (int r = 0; r < 4; ++r) {
                    const int key = kt0 + j4 * 16 + quad * 4 + r;
                    sv[j4][r] = (key > qrow) ? -1e30f : sacc[j4][r] * SCALE;
                }
        } else {
#pragma unroll
            for (int j4 = 0; j4 < 4; ++j4)
#pragma unroll
                for (int r = 0; r < 4; ++r)
                    sv[j4][r] = sacc[j4][r] * SCALE;
        }

        // online softmax: in-lane max over 16 + 2 cross-quad shuffles
        float mx = -1e30f;
#pragma unroll
        for (int j4 = 0; j4 < 4; ++j4)
#pragma unroll
            for (int r = 0; r < 4; ++r) mx = fmaxf(mx, sv[j4][r]);
        mx = fmaxf(mx, __shfl_xor(mx, 16, 64));
        mx = fmaxf(mx, __shfl_xor(mx, 32, 64));
        const float mn = fmaxf(m_c, mx);
        const float alpha = __expf(m_c - mn);
        float ps = 0.0f;
#pragma unroll
        for (int j4 = 0; j4 < 4; ++j4)
#pragma unroll
            for (int r = 0; r < 4; ++r) {
                const float pe = __expf(sv[j4][r] - mn);
                sv[j4][r] = pe;
                ps += pe;
            }
        ps += __shfl_xor(ps, 16, 64);
        ps += __shfl_xor(ps, 32, 64);
        l_c = l_c * alpha + ps;
        m_c = mn;
#pragma unroll
        for (int dt = 0; dt < 8; ++dt) o_c[dt] *= alpha;

        // O^T += V^T * P^T : per ks, pack P into per-wave frag then 8 MFMA
#pragma unroll
        for (int ks = 0; ks < 2; ++ks) {
#pragma unroll
            for (int jj = 0; jj < 2; ++jj) {
                const int j4 = ks * 2 + jj;
#pragma unroll
                for (int p = 0; p < 2; ++p) {
                    const int k_in = jj * 16 + quad * 4 + p * 2;
                    const u32 pk = ((u32)f2bf(sv[j4][p * 2 + 1]) << 16) | f2bf(sv[j4][p * 2]);
                    *(u32*)(sP + w * 512 + ((k_in >> 3) * 16 + l15) * 8 + (k_in & 7)) = pk;
                }
            }
            const bf16x8 pf = *(const bf16x8*)(sP + w * 512 + lane * 8);
#pragma unroll
            for (int dt = 0; dt < 8; ++dt) {
                const bf16x8 vf = *(const bf16x8*)(sV + (dt * 2 + ks) * 512 + lane * 8);
                o_c[dt] = MFMA16(vf, pf, o_c[dt]);
            }
        }
    }

    // epilogue: part [tile][d=128][qrow=64] fp16 + (m,l) fp32
    const float invl = 1.0f / l_c;
#pragma unroll
    for (int dt = 0; dt < 8; ++dt)
#pragma unroll
        for (int r = 0; r < 4; ++r)
            part[(size_t)bid * 8192 + (dt * 16 + quad * 4 + r) * 64 + w * 16 + l15] =
                f2h(o_c[dt][r] * invl);
    if (quad == 0) {
        ml[(size_t)bid * 128 + (w * 16 + l15) * 2] = m_c;
        ml[(size_t)bid * 128 + (w * 16 + l15) * 2 + 1] = l_c;
    }
}

// ---------------------------------------------------------------- merge partials
// grid 1024 (qb*16+h); thread: qrow = t&63 (coalesced part reads), d = (t>>6)*32..+31.
// Applies reference merge IN CHUNK ORDER: d = a + sE + 1e-10; o = o*(l_g/d) + ohat*sE/d.
__global__ __launch_bounds__(256) void attn_merge(const u16* __restrict__ part,
                                                  const float* __restrict__ ml,
                                                  u16* __restrict__ attn) {
    const int b = blockIdx.x;
    const int qb = b >> 4, h = b & 15;
    const int g = qb >> 4, k15 = qb & 15;
    const int t = threadIdx.x;
    const int qrow = t & 63, dg = t >> 6;

    float o[32];
#pragma unroll
    for (int i = 0; i < 32; ++i) o[i] = 0.0f;
    float m_g = -1e30f, l_g = 0.0f;

    for (int c = 0; c <= g; ++c) {
        int u;
        if (c == g)      u = 96 + (15 - k15) * 4 + g;
        else if (g == 1) u = qb - 16;
        else if (g == 2) u = 16 + (qb - 32) * 2 + c;
        else             u = 48 + (qb - 48) * 3 + c;
        const int tile = u * 16 + h;
        const float m_c = ml[(size_t)tile * 128 + qrow * 2];
        const float l_c = ml[(size_t)tile * 128 + qrow * 2 + 1];
        const float mn = fmaxf(m_g, m_c);
        const float a = l_g * __expf(m_g - mn);
        const float eC = __expf(m_c - mn);
        const float sE = l_c * eC;
        const float d = a + sE + 1e-10f;
        const float f_old = l_g / d;
        const float f_new = sE / d;
#pragma unroll
        for (int i = 0; i < 32; ++i) {
            const float v = h2f(part[(size_t)tile * 8192 + (dg * 32 + i) * 64 + qrow]);
            o[i] = o[i] * f_old + v * f_new;
        }
        l_g = a + sE;
        m_g = mn;
    }

    u16* dst = attn + (size_t)(qb * 64 + qrow) * 2048 + h * 128 + dg * 32;
#pragma unroll
    for (int kq = 0; kq < 4; ++kq) {
        union { u16 s[8]; uint4 v; } pk;
#pragma unroll
        for (int i = 0; i < 8; ++i) pk.s[i] = f2bf(o[kq * 8 + i]);
        *(uint4*)(dst + kq * 8) = pk.v;
    }
}

// ---------------------------------------------------------------- launch
extern "C" void kernel_launch(void* const* d_in, const int* in_sizes, int n_in,
                              void* d_out, int out_size, void* d_ws, size_t ws_size,
                              hipStream_t stream) {
    const float* X  = (const float*)d_in[0];
    const int* pos  = (const int*)d_in[1];
    const float* Wq = (const float*)d_in[2];
    const float* Wk = (const float*)d_in[3];
    const float* Wv = (const float*)d_in[4];
    const float* Wo = (const float*)d_in[5];
    float* out = (float*)d_out;
    char* ws = (char*)d_ws;

    u16*   part = (u16*)(ws);
    u16*   Xbf  = (u16*)(ws);                      // overlay (dead before part)
    u16*   Wqt  = (u16*)(ws + 16777216);
    u16*   Wkvt = (u16*)(ws + 25165824);
    u16*   Qbf  = (u16*)(ws + 41943040);
    u16*   attn = (u16*)(ws + 41943040);           // overlay Qbf (dead after partials)
    u16*   KVbf = (u16*)(ws + 58720256);
    u16*   Vt   = (u16*)(ws + 67108864);
    float* ml   = (float*)(ws + 71303168);
    u16*   Wot  = (u16*)(ws + 72613888);

    convert_f32_bf16<<<8192, 256, 0, stream>>>(X, Xbf);
    transpose_w<<<dim3(32, 32), 256, 0, stream>>>(Wq, Wqt, 2048);
    transpose_w<<<dim3(8, 32), 256, 0, stream>>>(Wk, Wkvt, 512);
    transpose_w<<<dim3(8, 32), 256, 0, stream>>>(Wv, Wkvt + (size_t)512 * 2048, 512);
    transpose_w<<<dim3(32, 32), 256, 0, stream>>>(Wo, Wot, 2048);

    gemm_bt<u16><<<dim3(32, 16), 256, 0, stream>>>(Xbf, Wqt, Qbf, 4096, 2048, 2048);
    gemm_bt<u16><<<dim3(32, 8), 256, 0, stream>>>(Xbf, Wkvt, KVbf, 4096, 1024, 2048);

    rope_kernel<<<20480, 256, 0, stream>>>(Qbf, KVbf, pos);
    transpose_v<<<dim3(64, 2, 4), 256, 0, stream>>>(KVbf, Vt);

    attn_partial<<<2560, 256, 0, stream>>>(Qbf, KVbf, Vt, part, ml);
    attn_merge<<<1024, 256, 0, stream>>>(part, ml, attn);

    gemm_bt<float><<<dim3(32, 16), 256, 0, stream>>>(attn, Wot, out, 4096, 2048, 2048);
}